// Round 22
// baseline (88.751 us; speedup 1.0000x reference)
//
#include <hip/hip_runtime.h>
#include <math.h>

// Problem constants (fixed-shape problem)
#define NPTS 8192
#define CCH  128
#define KNN  16
#define BN_RS 0.9999950000374997f   // 1/sqrt(1 + 1e-5)

typedef unsigned long long u64;
typedef unsigned short u16;
typedef __attribute__((ext_vector_type(8))) short short8;
typedef __attribute__((ext_vector_type(4))) float f32x4;

__device__ __forceinline__ u16 f2bf(float f) {   // round-to-nearest-even
    unsigned u = __float_as_uint(f);
    u += 0x7FFFu + ((u >> 16) & 1u);
    return (u16)(u >> 16);
}

__device__ __forceinline__ void bf8_to_f(const uint4 u, float* f) {
    f[0] = __uint_as_float(u.x << 16); f[1] = __uint_as_float(u.x & 0xffff0000u);
    f[2] = __uint_as_float(u.y << 16); f[3] = __uint_as_float(u.y & 0xffff0000u);
    f[4] = __uint_as_float(u.z << 16); f[5] = __uint_as_float(u.z & 0xffff0000u);
    f[6] = __uint_as_float(u.w << 16); f[7] = __uint_as_float(u.w & 0xffff0000u);
}

__device__ __forceinline__ short8 pack8(const float4 a, const float4 b) {
    short8 s;
    s[0] = (short)f2bf(a.x); s[1] = (short)f2bf(a.y);
    s[2] = (short)f2bf(a.z); s[3] = (short)f2bf(a.w);
    s[4] = (short)f2bf(b.x); s[5] = (short)f2bf(b.y);
    s[6] = (short)f2bf(b.z); s[7] = (short)f2bf(b.w);
    return s;
}

// ---------------------------------------------------------------------------
// Kernel P: pack candidates as float4 (x,y,z,|p|^2).
// Block 0: prepacks Ww1/Ww2 bf16 fragments for fused (R16, verified layout).
// Blocks 1..24: prepack Wq/Wk/Wv into bf16 B-fragment layout for MFMA gemm.
// ---------------------------------------------------------------------------
__global__ __launch_bounds__(256) void pack_kernel(const float* __restrict__ p,
                                                   float4* __restrict__ c4,
                                                   const float* __restrict__ Ww1,
                                                   const float* __restrict__ Ww2,
                                                   const float* __restrict__ Wq,
                                                   const float* __restrict__ Wk,
                                                   const float* __restrict__ Wv,
                                                   u16* __restrict__ w1p,
                                                   u16* __restrict__ w2p,
                                                   u16* __restrict__ wpack) {
    const int t = threadIdx.x;
    const int j = blockIdx.x * 256 + t;
    if (j < NPTS) {
        const float x = p[3 * j + 0], y = p[3 * j + 1], z = p[3 * j + 2];
        c4[j] = make_float4(x, y, z, x * x + y * y + z * z);
    }
    if (blockIdx.x == 0) {
        {
            const int lg = t >> 7, rem = t & 127, lr = rem >> 3, e = rem & 7;
            w2p[t] = f2bf(Ww2[((lg * 8 + e) * 16 + lr) & 255]);
        }
        #pragma unroll
        for (int jj = 0; jj < 8; ++jj) {
            const int e2 = t + jj * 256;
            const int m = e2 & 15, c = e2 >> 4;
            const int byte = m * 256 + ((c * 2) ^ ((m & 7) << 4));
            w1p[byte >> 1] = f2bf(Ww1[e2]);
        }
    } else if (blockIdx.x <= 24) {
        const int g0 = (blockIdx.x - 1) * 2048;
        #pragma unroll
        for (int jj = 0; jj < 8; ++jj) {
            const int g   = g0 + t + jj * 256;
            const int m   = g >> 14;
            const int u   = g & 16383;
            const int e   = u & 7;
            const int l   = (u >> 3) & 63;
            const int kc  = (u >> 9) & 3;
            const int ccg = (u >> 11) & 7;
            const int k   = kc * 32 + ((l >> 4) << 3) + e;
            const int col = ccg * 16 + (l & 15);
            const float* W = (m == 0) ? Wq : (m == 1) ? Wk : Wv;
            wpack[g] = f2bf(W[k * CCH + col]);
        }
    }
}

// ---------------------------------------------------------------------------
// Merged KNN + GEMM dispatch (R22): INTERLEAVED 4:3 block mapping.
// Groups of 7 blocks: u<4 -> knn (31.7 KB LDS), u>=4 -> gemm (ZERO LDS).
// Per CU: 7 blocks = 4 knn (127 KB <= 160) + 3 gemm — all co-resident, so
// gemm's MFMA/VMEM waves genuinely fill knn's ~50% idle issue slots (R21's
// append-mapping ran gemm as a serial tail; R6's version of this mapping
// failed only because its gemm body needed 34.8 KB LDS — that's gone).
// ---------------------------------------------------------------------------
#define QPB   8
#define CAP   104
#define TILE  1024
#define SAMPN 4096

__device__ __forceinline__ u64 bitonic64(u64 v, const int lane) {
    #pragma unroll
    for (int k = 2; k <= 64; k <<= 1) {
        #pragma unroll
        for (int j = k >> 1; j > 0; j >>= 1) {
            const u64  o       = __shfl_xor(v, j);
            const bool takemin = (((lane & j) == 0) == ((lane & k) == 0));
            v = ((o < v) == takemin) ? o : v;
        }
    }
    return v;
}

__device__ __forceinline__ float bitonicf(float v, const int lane) {
    #pragma unroll
    for (int k = 2; k <= 64; k <<= 1) {
        #pragma unroll
        for (int j = k >> 1; j > 0; j >>= 1) {
            const float o      = __shfl_xor(v, j);
            const bool takemin = (((lane & j) == 0) == ((lane & k) == 0));
            v = ((o < v) == takemin) ? o : v;
        }
    }
    return v;
}

__device__ __forceinline__ float make_d2(const float4 c, const float m2x, const float m2y,
                                         const float m2z, const float qb) {
    float d2 = fmaf(m2x, c.x, fmaf(m2y, c.y, fmaf(m2z, c.z, c.w + qb)));
    return fmaxf(d2, 0.0f);
}

__global__ __launch_bounds__(256) void knn_gemm_kernel(
    const float4* __restrict__ c4, int* __restrict__ oidx, float* __restrict__ od2,
    const float* __restrict__ x,
    const float* __restrict__ bq, const float* __restrict__ bk,
    const float* __restrict__ bv, const u16* __restrict__ wpack,
    float* __restrict__ xq, u16* __restrict__ xk16, u16* __restrict__ xv16) {
    __shared__ float4 s_pt[TILE];          // 16 KB
    __shared__ float  s_min[QPB][256];     // 8 KB
    __shared__ float  s_tau[QPB];
    __shared__ u64    s_col[QPB][CAP];     // 6.5 KB
    __shared__ int    s_cnt[QPB];

    const int t    = threadIdx.x;
    const int wave = t >> 6;
    const int lane = t & 63;

    const int grp = blockIdx.x / 7;
    const int u7  = blockIdx.x % 7;

    if (u7 >= 4) {
        // ================= GEMM body (R19/R20 verbatim, zero LDS) ==========
        const int gbid  = grp * 3 + (u7 - 4);      // 0..767
        const int which = gbid >> 8;               // 0..2
        const int rem   = gbid & 255;
        const float* bias = (which == 0) ? bq : (which == 1) ? bk : bv;

        const int lr = lane & 15;
        const int lg = lane >> 4;
        const int row0 = (rem & 127) * 64 + wave * 16;
        const int col0 = (rem >> 7) * 64;

        short8 afr[4];
        #pragma unroll
        for (int kc = 0; kc < 4; ++kc) {
            const float4 a0 = *(const float4*)&x[(size_t)(row0 + lr) * CCH + kc * 32 + lg * 8];
            const float4 a1 = *(const float4*)&x[(size_t)(row0 + lr) * CCH + kc * 32 + lg * 8 + 4];
            afr[kc] = pack8(a0, a1);
        }

        f32x4 acc[4] = {{0.f,0.f,0.f,0.f},{0.f,0.f,0.f,0.f},
                        {0.f,0.f,0.f,0.f},{0.f,0.f,0.f,0.f}};
        const u16* wp = wpack + which * 16384;
        #pragma unroll
        for (int cc = 0; cc < 4; ++cc) {
            const int ccg = (col0 >> 4) + cc;
            #pragma unroll
            for (int kc = 0; kc < 4; ++kc) {
                const short8 b = *(const short8*)&wp[((ccg * 4 + kc) * 64 + lane) * 8];
                acc[cc] = __builtin_amdgcn_mfma_f32_16x16x32_bf16(afr[kc], b, acc[cc], 0, 0, 0);
            }
        }

        #pragma unroll
        for (int cc = 0; cc < 4; ++cc) {
            const int col = col0 + cc * 16 + lr;
            const float bb = bias[col];
            if (which == 0) {
                #pragma unroll
                for (int r = 0; r < 4; ++r)
                    xq[(size_t)(row0 + lg * 4 + r) * CCH + col] = acc[cc][r] + bb;
            } else {
                u16* o16 = (which == 1) ? xk16 : xv16;
                #pragma unroll
                for (int r = 0; r < 4; ++r)
                    o16[(size_t)(row0 + lg * 4 + r) * CCH + col] = f2bf(acc[cc][r] + bb);
            }
        }
        return;
    }

    // ==================== KNN body (R18/R20 verbatim) ======================
    const int qbase = (grp * 4 + u7) * QPB;

    float m2x[QPB], m2y[QPB], m2z[QPB], qb[QPB];
    #pragma unroll
    for (int qi = 0; qi < QPB; ++qi) {
        const float4 q = c4[qbase + qi];
        m2x[qi] = -2.0f * q.x;
        m2y[qi] = -2.0f * q.y;
        m2z[qi] = -2.0f * q.z;
        qb[qi]  = q.w;
    }
    if (t < QPB) s_cnt[t] = 0;             // synced by first staging barrier

    // ---- phase A: lane minima, wave scans its QUARTER for all 8 queries ----
    float bd[QPB];
    #pragma unroll
    for (int qi = 0; qi < QPB; ++qi) bd[qi] = 3.0e38f;

    const int base = wave * (TILE / 4);
    for (int tb = 0; tb < SAMPN; tb += TILE) {
        __syncthreads();
        #pragma unroll
        for (int jj = 0; jj < 4; ++jj) s_pt[t + jj * 256] = c4[tb + t + jj * 256];
        __syncthreads();
        #pragma unroll
        for (int it = 0; it < 4; ++it) {
            const float4 c = s_pt[base + it * 64 + lane];
            #pragma unroll
            for (int qi = 0; qi < QPB; ++qi)
                bd[qi] = fminf(bd[qi], make_d2(c, m2x[qi], m2y[qi], m2z[qi], qb[qi]));
        }
    }

    // ---- tau: dump lane-minima; recombine min-over-waves at fixed lane ----
    #pragma unroll
    for (int qi = 0; qi < QPB; ++qi) s_min[qi][t] = bd[qi];
    __syncthreads();
    #pragma unroll
    for (int u = 0; u < 2; ++u) {
        const int qi = wave * 2 + u;
        float v = fminf(fminf(s_min[qi][lane], s_min[qi][64 + lane]),
                        fminf(s_min[qi][128 + lane], s_min[qi][192 + lane]));
        v = bitonicf(v, lane);
        if (lane == 15) s_tau[qi] = v;     // 16th smallest
    }
    __syncthreads();
    float tauf[QPB];
    #pragma unroll
    for (int qi = 0; qi < QPB; ++qi) tauf[qi] = s_tau[qi];

    // ---- phase B: collect pass, same quarter-split ----
    for (int tb = 0; tb < NPTS; tb += TILE) {
        __syncthreads();
        #pragma unroll
        for (int jj = 0; jj < 4; ++jj) s_pt[t + jj * 256] = c4[tb + t + jj * 256];
        __syncthreads();
        #pragma unroll
        for (int it = 0; it < 4; ++it) {
            const int idx = base + it * 64 + lane;
            const float4 c = s_pt[idx];
            const int j = tb + idx;
            #pragma unroll
            for (int qi = 0; qi < QPB; ++qi) {
                const float d = make_d2(c, m2x[qi], m2y[qi], m2z[qi], qb[qi]);
                if (d <= tauf[qi]) {
                    const int pos = atomicAdd(&s_cnt[qi], 1);
                    if (pos < CAP)
                        s_col[qi][pos] = ((u64)__float_as_uint(d) << 32) | (u64)(unsigned)j;
                }
            }
        }
    }
    __syncthreads();

    // ---- final select: wave w owns queries 2w, 2w+1 ----
    #pragma unroll 1
    for (int u = 0; u < 2; ++u) {
        const int qi = wave * 2 + u;
        const int q  = qbase + qi;
        int M = s_cnt[qi];

        if (M > CAP) {
            // exact fallback (exercised ~never): full lane-min -> tight tau
            float fb = 3.0e38f;
            for (int l = lane; l < NPTS; l += 64)
                fb = fminf(fb, make_d2(c4[l], m2x[qi], m2y[qi], m2z[qi], qb[qi]));
            const float s    = bitonicf(fb, lane);
            const float tau2 = __shfl(s, 15);
            if (lane == 0) s_cnt[qi] = 0;  // wave-private query; LDS in-order
            for (int l = lane; l < NPTS; l += 64) {
                const float d = make_d2(c4[l], m2x[qi], m2y[qi], m2z[qi], qb[qi]);
                if (d <= tau2) {
                    const int pos = atomicAdd(&s_cnt[qi], 1);
                    if (pos < CAP)
                        s_col[qi][pos] = ((u64)__float_as_uint(d) << 32) | (u64)(unsigned)l;
                }
            }
            M = s_cnt[qi];
            if (M > CAP) M = CAP;
        }

        if (M <= 64) {
            u64 v = (lane < M) ? s_col[qi][lane] : ~0ull;
            v = bitonic64(v, lane);
            if (lane < KNN) {
                oidx[q * KNN + lane] = (int)(v & 0xffffffffu);
                od2 [q * KNN + lane] = __uint_as_float((unsigned)(v >> 32));
            }
        } else {
            u64 a = (lane < M) ? s_col[qi][lane] : ~0ull;
            a = bitonic64(a, lane);
            u64 b = (lane + 64 < M) ? s_col[qi][lane + 64] : ~0ull;
            b = bitonic64(b, lane);
            const u64 bs = __shfl(b, lane & 15);
            u64 mv = (lane < 16) ? a : ((lane < 32) ? bs : ~0ull);
            mv = bitonic64(mv, lane);
            if (lane < KNN) {
                oidx[q * KNN + lane] = (int)(mv & 0xffffffffu);
                od2 [q * KNN + lane] = __uint_as_float((unsigned)(mv >> 32));
            }
        }
    }
}

// ---------------------------------------------------------------------------
// Kernel C: fused per-point attention, v10 (R16 version, verbatim).
// ---------------------------------------------------------------------------
__global__ __launch_bounds__(256) void fused_kernel(
    const float* __restrict__ p,
    const float* __restrict__ xqg, const u16* __restrict__ xkg, const u16* __restrict__ xvg,
    const int* __restrict__ nidx, const float* __restrict__ nd2,
    const float* __restrict__ Wp1, const float* __restrict__ bp1,
    const float* __restrict__ g1,  const float* __restrict__ be1,
    const float* __restrict__ Wp2, const float* __restrict__ bp2,
    const float* __restrict__ g2,  const float* __restrict__ be2,
    const u16* __restrict__ w1p,   const float* __restrict__ bw1,
    const float* __restrict__ g3,  const float* __restrict__ be3,
    const u16* __restrict__ w2p,   const float* __restrict__ bw2,
    float* __restrict__ out) {
    const int i = blockIdx.x;
    const int t = threadIdx.x;

    __shared__ __align__(16) u16 s_wv[2048];    // [16 nbr][128 ch] bf16, swizzled
    __shared__ __align__(16) u16 s_rr[256];     // [16 nbr][16 m]  bf16, plain
    __shared__ float s_val[16][132];
    __shared__ float s_wnT[16][20];             // [m][nbr] (transposed)

    const int k  = t >> 4;      // neighbor 0..15
    const int tl = t & 15;      // channel-group
    const int c0 = tl * 8;

    // ---- issue long-latency gathers first ----
    const int   jn  = nidx[i * KNN + k];
    const float d2v = nd2[i * KNN + k];
    const uint4 ku = *(const uint4*)&xkg[(size_t)jn * CCH + c0];   // 8 bf16
    const uint4 vu = *(const uint4*)&xvg[(size_t)jn * CCH + c0];   // 8 bf16

    // ---- phase 1: pr + wv (regs) + val (LDS) ----
    const float dw  = __expf(-sqrtf(fmaxf(d2v, 0.f)));
    const float prx = p[jn * 3 + 0] - p[i * 3 + 0];
    const float pry = p[jn * 3 + 1] - p[i * 3 + 1];
    const float prz = p[jn * 3 + 2] - p[i * 3 + 2];
    float tt[3];
    #pragma unroll
    for (int e = 0; e < 3; ++e) {
        float v = prx * Wp1[0 * 3 + e] + pry * Wp1[1 * 3 + e] + prz * Wp1[2 * 3 + e] + bp1[e];
        v = v * (g1[e] * BN_RS) + be1[e];
        tt[e] = fmaxf(v, 0.f);
    }

    float xk8[8], xv8[8];
    bf8_to_f(ku, xk8);
    bf8_to_f(vu, xv8);

    float wv8[8];
    #pragma unroll
    for (int h = 0; h < 2; ++h) {
        const int cc = c0 + h * 4;
        const float4 w0  = *(const float4*)&Wp2[cc];
        const float4 w1  = *(const float4*)&Wp2[128 + cc];
        const float4 w2  = *(const float4*)&Wp2[256 + cc];
        const float4 bp  = *(const float4*)&bp2[cc];
        const float4 xq4 = *(const float4*)&xqg[(size_t)i * CCH + cc];
        const float4 gg  = *(const float4*)&g2[cc];
        const float4 bb  = *(const float4*)&be2[cc];
        float4 val4;
        {
            const float pr = tt[0] * w0.x + tt[1] * w1.x + tt[2] * w2.x + bp.x;
            wv8[h * 4 + 0] = fmaxf(((xq4.x - xk8[h * 4 + 0]) + pr) * (gg.x * BN_RS) + bb.x, 0.f);
            val4.x = xv8[h * 4 + 0] * dw + pr;
        }
        {
            const float pr = tt[0] * w0.y + tt[1] * w1.y + tt[2] * w2.y + bp.y;
            wv8[h * 4 + 1] = fmaxf(((xq4.y - xk8[h * 4 + 1]) + pr) * (gg.y * BN_RS) + bb.y, 0.f);
            val4.y = xv8[h * 4 + 1] * dw + pr;
        }
        {
            const float pr = tt[0] * w0.z + tt[1] * w1.z + tt[2] * w2.z + bp.z;
            wv8[h * 4 + 2] = fmaxf(((xq4.z - xk8[h * 4 + 2]) + pr) * (gg.z * BN_RS) + bb.z, 0.f);
            val4.z = xv8[h * 4 + 2] * dw + pr;
        }
        {
            const float pr = tt[0] * w0.w + tt[1] * w1.w + tt[2] * w2.w + bp.w;
            wv8[h * 4 + 3] = fmaxf(((xq4.w - xk8[h * 4 + 3]) + pr) * (gg.w * BN_RS) + bb.w, 0.f);
            val4.w = xv8[h * 4 + 3] * dw + pr;
        }
        *(float4*)&s_val[k][cc] = val4;
    }

    // wv -> bf16 -> s_wv, swizzled, one b128 write
    {
        uint4 wp;
        wp.x = (unsigned)f2bf(wv8[0]) | ((unsigned)f2bf(wv8[1]) << 16);
        wp.y = (unsigned)f2bf(wv8[2]) | ((unsigned)f2bf(wv8[3]) << 16);
        wp.z = (unsigned)f2bf(wv8[4]) | ((unsigned)f2bf(wv8[5]) << 16);
        wp.w = (unsigned)f2bf(wv8[6]) | ((unsigned)f2bf(wv8[7]) << 16);
        const int byte = k * 256 + ((c0 * 2) ^ ((k & 7) << 4));
        *(uint4*)((char*)s_wv + byte) = wp;
    }
    __syncthreads();                                   // B0

    // ---- wave 0 only: MFMA w-MLP + softmax ----
    if (t < 64) {
        const int l  = t;
        const int lr = l & 15;      // A row / B col
        const int lg = l >> 4;      // k-chunk group

        f32x4 acc = {0.f, 0.f, 0.f, 0.f};
        #pragma unroll
        for (int c = 0; c < 4; ++c) {
            const int off = ((lg * 16 + 64 * c) ^ ((lr & 7) << 4));
            const short8 a = *(const short8*)((const char*)s_wv + lr * 256 + off);
            const short8 b = *(const short8*)((const char*)w1p  + lr * 256 + off);
            acc = __builtin_amdgcn_mfma_f32_16x16x32_bf16(a, b, acc, 0, 0, 0);
        }
        const float bw1m = bw1[lr];
        const float g3m  = g3[lr] * BN_RS;
        const float be3m = be3[lr];
        #pragma unroll
        for (int r = 0; r < 4; ++r) {
            const float rr = fmaxf((acc[r] + bw1m) * g3m + be3m, 0.f);
            *(u16*)((char*)s_rr + (lg * 4 + r) * 32 + lr * 2) = f2bf(rr);
        }

        short8 a2 = (short8){0, 0, 0, 0, 0, 0, 0, 0};
        short8 b2 = (short8){0, 0, 0, 0, 0, 0, 0, 0};
        if (lg < 2) {
            a2 = *(const short8*)((const char*)s_rr + lr * 32 + lg * 16);
            b2 = *(const short8*)((const char*)w2p + (lg * 16 + lr) * 16);
        }
        f32x4 acc2 = {0.f, 0.f, 0.f, 0.f};
        acc2 = __builtin_amdgcn_mfma_f32_16x16x32_bf16(a2, b2, acc2, 0, 0, 0);

        const float bw2m = bw2[lr];
        float w2v[4];
        #pragma unroll
        for (int r = 0; r < 4; ++r) w2v[r] = acc2[r] + bw2m;

        float mx = fmaxf(fmaxf(w2v[0], w2v[1]), fmaxf(w2v[2], w2v[3]));
        mx = fmaxf(mx, __shfl_xor(mx, 16));
        mx = fmaxf(mx, __shfl_xor(mx, 32));
        float ev[4], ss = 0.f;
        #pragma unroll
        for (int r = 0; r < 4; ++r) { ev[r] = __expf(w2v[r] - mx); ss += ev[r]; }
        ss += __shfl_xor(ss, 16);
        ss += __shfl_xor(ss, 32);
        const float inv = __fdividef(1.f, ss);
        #pragma unroll
        for (int r = 0; r < 4; ++r) s_wnT[lr][lg * 4 + r] = ev[r] * inv;
    }
    __syncthreads();                                   // B1

    // ---- phase 4: out[c] = sum_k val[k][c] * wnT[c & 15][k] ----
    if (t < 128) {
        const int c = t, mc = t & 15;
        const float4 wn0 = *(const float4*)&s_wnT[mc][0];
        const float4 wn1 = *(const float4*)&s_wnT[mc][4];
        const float4 wn2 = *(const float4*)&s_wnT[mc][8];
        const float4 wn3 = *(const float4*)&s_wnT[mc][12];
        float o = 0.f;
        o += s_val[0][c]  * wn0.x; o += s_val[1][c]  * wn0.y;
        o += s_val[2][c]  * wn0.z; o += s_val[3][c]  * wn0.w;
        o += s_val[4][c]  * wn1.x; o += s_val[5][c]  * wn1.y;
        o += s_val[6][c]  * wn1.z; o += s_val[7][c]  * wn1.w;
        o += s_val[8][c]  * wn2.x; o += s_val[9][c]  * wn2.y;
        o += s_val[10][c] * wn2.z; o += s_val[11][c] * wn2.w;
        o += s_val[12][c] * wn3.x; o += s_val[13][c] * wn3.y;
        o += s_val[14][c] * wn3.z; o += s_val[15][c] * wn3.w;
        out[(size_t)i * CCH + c] = o;
    }
}

// ---------------------------------------------------------------------------
extern "C" void kernel_launch(void* const* d_in, const int* in_sizes, int n_in,
                              void* d_out, int out_size, void* d_ws, size_t ws_size,
                              hipStream_t stream) {
    (void)in_sizes; (void)n_in; (void)out_size; (void)ws_size;
    const float* p   = (const float*)d_in[0];
    const float* x   = (const float*)d_in[1];
    const float* Wq  = (const float*)d_in[2];
    const float* bq  = (const float*)d_in[3];
    const float* Wk  = (const float*)d_in[4];
    const float* bk  = (const float*)d_in[5];
    const float* Wv  = (const float*)d_in[6];
    const float* bv  = (const float*)d_in[7];
    const float* Wp1 = (const float*)d_in[8];
    const float* bp1 = (const float*)d_in[9];
    const float* g1  = (const float*)d_in[10];
    const float* be1 = (const float*)d_in[11];
    const float* Wp2 = (const float*)d_in[12];
    const float* bp2 = (const float*)d_in[13];
    const float* g2  = (const float*)d_in[14];
    const float* be2 = (const float*)d_in[15];
    const float* Ww1 = (const float*)d_in[16];
    const float* bw1 = (const float*)d_in[17];
    const float* g3  = (const float*)d_in[18];
    const float* be3 = (const float*)d_in[19];
    const float* Ww2 = (const float*)d_in[20];
    const float* bw2 = (const float*)d_in[21];
    float* out = (float*)d_out;

    // workspace layout
    char* ws = (char*)d_ws;
    int*    idxb  = (int*)ws;                                   // 512 KB
    float*  d2b   = (float*)(ws + (size_t)512 * 1024);          // 512 KB
    float*  xqb   = (float*)(ws + (size_t)1 * 1024 * 1024);     // 4 MB
    u16*    xkb16 = (u16*)(ws + (size_t)5 * 1024 * 1024);       // 2 MB
    u16*    xvb16 = (u16*)(ws + (size_t)7 * 1024 * 1024);       // 2 MB
    float4* c4b   = (float4*)(ws + (size_t)9 * 1024 * 1024);    // 128 KB
    u16*    w1p   = (u16*)(ws + (size_t)9 * 1024 * 1024 + 128 * 1024);   // 4 KB
    u16*    w2p   = (u16*)(ws + (size_t)9 * 1024 * 1024 + 132 * 1024);   // 512 B
    u16*    wpack = (u16*)(ws + (size_t)9 * 1024 * 1024 + 136 * 1024);   // 96 KB

    pack_kernel<<<dim3(NPTS / 256), dim3(256), 0, stream>>>(
        p, c4b, Ww1, Ww2, Wq, Wk, Wv, w1p, w2p, wpack);
    knn_gemm_kernel<<<dim3(1792), dim3(256), 0, stream>>>(
        c4b, idxb, d2b, x, bq, bk, bv, wpack, xqb, xkb16, xvb16);
    fused_kernel<<<dim3(NPTS), dim3(256), 0, stream>>>(
        p, xqb, xkb16, xvb16, idxb, d2b,
        Wp1, bp1, g1, be1, Wp2, bp2, g2, be2, w1p, bw1, g3, be3, w2p, bw2, out);
}

// Round 23
// 71.500 us; speedup vs baseline: 1.2413x; 1.2413x over previous
//
#include <hip/hip_runtime.h>
#include <math.h>

// Problem constants (fixed-shape problem)
#define NPTS 8192
#define CCH  128
#define KNN  16
#define BN_RS 0.9999950000374997f   // 1/sqrt(1 + 1e-5)

typedef unsigned long long u64;
typedef unsigned short u16;
typedef __attribute__((ext_vector_type(8))) short short8;
typedef __attribute__((ext_vector_type(4))) float f32x4;

__device__ __forceinline__ u16 f2bf(float f) {   // round-to-nearest-even
    unsigned u = __float_as_uint(f);
    u += 0x7FFFu + ((u >> 16) & 1u);
    return (u16)(u >> 16);
}

__device__ __forceinline__ void bf8_to_f(const uint4 u, float* f) {
    f[0] = __uint_as_float(u.x << 16); f[1] = __uint_as_float(u.x & 0xffff0000u);
    f[2] = __uint_as_float(u.y << 16); f[3] = __uint_as_float(u.y & 0xffff0000u);
    f[4] = __uint_as_float(u.z << 16); f[5] = __uint_as_float(u.z & 0xffff0000u);
    f[6] = __uint_as_float(u.w << 16); f[7] = __uint_as_float(u.w & 0xffff0000u);
}

__device__ __forceinline__ short8 pack8(const float4 a, const float4 b) {
    short8 s;
    s[0] = (short)f2bf(a.x); s[1] = (short)f2bf(a.y);
    s[2] = (short)f2bf(a.z); s[3] = (short)f2bf(a.w);
    s[4] = (short)f2bf(b.x); s[5] = (short)f2bf(b.y);
    s[6] = (short)f2bf(b.z); s[7] = (short)f2bf(b.w);
    return s;
}

// ---------------------------------------------------------------------------
// Kernel P: pack candidates as float4 (x,y,z,|p|^2).
// Block 0: prepacks Ww1/Ww2 bf16 fragments for fused (R16, verified layout).
// Blocks 1..24: prepack Wq/Wk/Wv into bf16 B-fragment layout for MFMA gemm.
// ---------------------------------------------------------------------------
__global__ __launch_bounds__(256) void pack_kernel(const float* __restrict__ p,
                                                   float4* __restrict__ c4,
                                                   const float* __restrict__ Ww1,
                                                   const float* __restrict__ Ww2,
                                                   const float* __restrict__ Wq,
                                                   const float* __restrict__ Wk,
                                                   const float* __restrict__ Wv,
                                                   u16* __restrict__ w1p,
                                                   u16* __restrict__ w2p,
                                                   u16* __restrict__ wpack) {
    const int t = threadIdx.x;
    const int j = blockIdx.x * 256 + t;
    if (j < NPTS) {
        const float x = p[3 * j + 0], y = p[3 * j + 1], z = p[3 * j + 2];
        c4[j] = make_float4(x, y, z, x * x + y * y + z * z);
    }
    if (blockIdx.x == 0) {
        {
            const int lg = t >> 7, rem = t & 127, lr = rem >> 3, e = rem & 7;
            w2p[t] = f2bf(Ww2[((lg * 8 + e) * 16 + lr) & 255]);
        }
        #pragma unroll
        for (int jj = 0; jj < 8; ++jj) {
            const int e2 = t + jj * 256;
            const int m = e2 & 15, c = e2 >> 4;
            const int byte = m * 256 + ((c * 2) ^ ((m & 7) << 4));
            w1p[byte >> 1] = f2bf(Ww1[e2]);
        }
    } else if (blockIdx.x <= 24) {
        const int g0 = (blockIdx.x - 1) * 2048;
        #pragma unroll
        for (int jj = 0; jj < 8; ++jj) {
            const int g   = g0 + t + jj * 256;
            const int m   = g >> 14;
            const int u   = g & 16383;
            const int e   = u & 7;
            const int l   = (u >> 3) & 63;
            const int kc  = (u >> 9) & 3;
            const int ccg = (u >> 11) & 7;
            const int k   = kc * 32 + ((l >> 4) << 3) + e;
            const int col = ccg * 16 + (l & 15);
            const float* W = (m == 0) ? Wq : (m == 1) ? Wk : Wv;
            wpack[g] = f2bf(W[k * CCH + col]);
        }
    }
}

// ---------------------------------------------------------------------------
// Merged KNN + GEMM dispatch (R21 mapping, confirmed optimum).
// knn blocks: blockIdx < 1024 (31.7 KB LDS).  gemm blocks: >= 1024 (zero
// LDS), dispatched after — runs as a short tail; the merge's win is launch-
// gap elimination.  (R22's 4:3 interleave diluted knn occupancy: 60.7 us.)
// ---------------------------------------------------------------------------
#define QPB   8
#define CAP   104
#define TILE  1024
#define SAMPN 4096

__device__ __forceinline__ u64 bitonic64(u64 v, const int lane) {
    #pragma unroll
    for (int k = 2; k <= 64; k <<= 1) {
        #pragma unroll
        for (int j = k >> 1; j > 0; j >>= 1) {
            const u64  o       = __shfl_xor(v, j);
            const bool takemin = (((lane & j) == 0) == ((lane & k) == 0));
            v = ((o < v) == takemin) ? o : v;
        }
    }
    return v;
}

__device__ __forceinline__ float bitonicf(float v, const int lane) {
    #pragma unroll
    for (int k = 2; k <= 64; k <<= 1) {
        #pragma unroll
        for (int j = k >> 1; j > 0; j >>= 1) {
            const float o      = __shfl_xor(v, j);
            const bool takemin = (((lane & j) == 0) == ((lane & k) == 0));
            v = ((o < v) == takemin) ? o : v;
        }
    }
    return v;
}

__device__ __forceinline__ float make_d2(const float4 c, const float m2x, const float m2y,
                                         const float m2z, const float qb) {
    float d2 = fmaf(m2x, c.x, fmaf(m2y, c.y, fmaf(m2z, c.z, c.w + qb)));
    return fmaxf(d2, 0.0f);
}

__global__ __launch_bounds__(256) void knn_gemm_kernel(
    const float4* __restrict__ c4, int* __restrict__ oidx, float* __restrict__ od2,
    const float* __restrict__ x,
    const float* __restrict__ bq, const float* __restrict__ bk,
    const float* __restrict__ bv, const u16* __restrict__ wpack,
    float* __restrict__ xq, u16* __restrict__ xk16, u16* __restrict__ xv16) {
    __shared__ float4 s_pt[TILE];          // 16 KB
    __shared__ float  s_min[QPB][256];     // 8 KB
    __shared__ float  s_tau[QPB];
    __shared__ u64    s_col[QPB][CAP];     // 6.5 KB
    __shared__ int    s_cnt[QPB];

    const int t    = threadIdx.x;
    const int wave = t >> 6;
    const int lane = t & 63;

    if (blockIdx.x >= 1024) {
        // ================= GEMM body (R19/R20 verbatim, zero LDS) ==========
        const int gbid  = blockIdx.x - 1024;
        const int which = gbid >> 8;               // 0..2
        const int rem   = gbid & 255;
        const float* bias = (which == 0) ? bq : (which == 1) ? bk : bv;

        const int lr = lane & 15;
        const int lg = lane >> 4;
        const int row0 = (rem & 127) * 64 + wave * 16;
        const int col0 = (rem >> 7) * 64;

        short8 afr[4];
        #pragma unroll
        for (int kc = 0; kc < 4; ++kc) {
            const float4 a0 = *(const float4*)&x[(size_t)(row0 + lr) * CCH + kc * 32 + lg * 8];
            const float4 a1 = *(const float4*)&x[(size_t)(row0 + lr) * CCH + kc * 32 + lg * 8 + 4];
            afr[kc] = pack8(a0, a1);
        }

        f32x4 acc[4] = {{0.f,0.f,0.f,0.f},{0.f,0.f,0.f,0.f},
                        {0.f,0.f,0.f,0.f},{0.f,0.f,0.f,0.f}};
        const u16* wp = wpack + which * 16384;
        #pragma unroll
        for (int cc = 0; cc < 4; ++cc) {
            const int ccg = (col0 >> 4) + cc;
            #pragma unroll
            for (int kc = 0; kc < 4; ++kc) {
                const short8 b = *(const short8*)&wp[((ccg * 4 + kc) * 64 + lane) * 8];
                acc[cc] = __builtin_amdgcn_mfma_f32_16x16x32_bf16(afr[kc], b, acc[cc], 0, 0, 0);
            }
        }

        #pragma unroll
        for (int cc = 0; cc < 4; ++cc) {
            const int col = col0 + cc * 16 + lr;
            const float bb = bias[col];
            if (which == 0) {
                #pragma unroll
                for (int r = 0; r < 4; ++r)
                    xq[(size_t)(row0 + lg * 4 + r) * CCH + col] = acc[cc][r] + bb;
            } else {
                u16* o16 = (which == 1) ? xk16 : xv16;
                #pragma unroll
                for (int r = 0; r < 4; ++r)
                    o16[(size_t)(row0 + lg * 4 + r) * CCH + col] = f2bf(acc[cc][r] + bb);
            }
        }
        return;
    }

    // ==================== KNN body (R18/R20 verbatim) ======================
    const int qbase = blockIdx.x * QPB;

    float m2x[QPB], m2y[QPB], m2z[QPB], qb[QPB];
    #pragma unroll
    for (int qi = 0; qi < QPB; ++qi) {
        const float4 q = c4[qbase + qi];
        m2x[qi] = -2.0f * q.x;
        m2y[qi] = -2.0f * q.y;
        m2z[qi] = -2.0f * q.z;
        qb[qi]  = q.w;
    }
    if (t < QPB) s_cnt[t] = 0;             // synced by first staging barrier

    // ---- phase A: lane minima, wave scans its QUARTER for all 8 queries ----
    float bd[QPB];
    #pragma unroll
    for (int qi = 0; qi < QPB; ++qi) bd[qi] = 3.0e38f;

    const int base = wave * (TILE / 4);
    for (int tb = 0; tb < SAMPN; tb += TILE) {
        __syncthreads();
        #pragma unroll
        for (int jj = 0; jj < 4; ++jj) s_pt[t + jj * 256] = c4[tb + t + jj * 256];
        __syncthreads();
        #pragma unroll
        for (int it = 0; it < 4; ++it) {
            const float4 c = s_pt[base + it * 64 + lane];
            #pragma unroll
            for (int qi = 0; qi < QPB; ++qi)
                bd[qi] = fminf(bd[qi], make_d2(c, m2x[qi], m2y[qi], m2z[qi], qb[qi]));
        }
    }

    // ---- tau: dump lane-minima; recombine min-over-waves at fixed lane ----
    #pragma unroll
    for (int qi = 0; qi < QPB; ++qi) s_min[qi][t] = bd[qi];
    __syncthreads();
    #pragma unroll
    for (int u = 0; u < 2; ++u) {
        const int qi = wave * 2 + u;
        float v = fminf(fminf(s_min[qi][lane], s_min[qi][64 + lane]),
                        fminf(s_min[qi][128 + lane], s_min[qi][192 + lane]));
        v = bitonicf(v, lane);
        if (lane == 15) s_tau[qi] = v;     // 16th smallest
    }
    __syncthreads();
    float tauf[QPB];
    #pragma unroll
    for (int qi = 0; qi < QPB; ++qi) tauf[qi] = s_tau[qi];

    // ---- phase B: collect pass, same quarter-split ----
    for (int tb = 0; tb < NPTS; tb += TILE) {
        __syncthreads();
        #pragma unroll
        for (int jj = 0; jj < 4; ++jj) s_pt[t + jj * 256] = c4[tb + t + jj * 256];
        __syncthreads();
        #pragma unroll
        for (int it = 0; it < 4; ++it) {
            const int idx = base + it * 64 + lane;
            const float4 c = s_pt[idx];
            const int j = tb + idx;
            #pragma unroll
            for (int qi = 0; qi < QPB; ++qi) {
                const float d = make_d2(c, m2x[qi], m2y[qi], m2z[qi], qb[qi]);
                if (d <= tauf[qi]) {
                    const int pos = atomicAdd(&s_cnt[qi], 1);
                    if (pos < CAP)
                        s_col[qi][pos] = ((u64)__float_as_uint(d) << 32) | (u64)(unsigned)j;
                }
            }
        }
    }
    __syncthreads();

    // ---- final select: wave w owns queries 2w, 2w+1 ----
    #pragma unroll 1
    for (int u = 0; u < 2; ++u) {
        const int qi = wave * 2 + u;
        const int q  = qbase + qi;
        int M = s_cnt[qi];

        if (M > CAP) {
            // exact fallback (exercised ~never): full lane-min -> tight tau
            float fb = 3.0e38f;
            for (int l = lane; l < NPTS; l += 64)
                fb = fminf(fb, make_d2(c4[l], m2x[qi], m2y[qi], m2z[qi], qb[qi]));
            const float s    = bitonicf(fb, lane);
            const float tau2 = __shfl(s, 15);
            if (lane == 0) s_cnt[qi] = 0;  // wave-private query; LDS in-order
            for (int l = lane; l < NPTS; l += 64) {
                const float d = make_d2(c4[l], m2x[qi], m2y[qi], m2z[qi], qb[qi]);
                if (d <= tau2) {
                    const int pos = atomicAdd(&s_cnt[qi], 1);
                    if (pos < CAP)
                        s_col[qi][pos] = ((u64)__float_as_uint(d) << 32) | (u64)(unsigned)l;
                }
            }
            M = s_cnt[qi];
            if (M > CAP) M = CAP;
        }

        if (M <= 64) {
            u64 v = (lane < M) ? s_col[qi][lane] : ~0ull;
            v = bitonic64(v, lane);
            if (lane < KNN) {
                oidx[q * KNN + lane] = (int)(v & 0xffffffffu);
                od2 [q * KNN + lane] = __uint_as_float((unsigned)(v >> 32));
            }
        } else {
            u64 a = (lane < M) ? s_col[qi][lane] : ~0ull;
            a = bitonic64(a, lane);
            u64 b = (lane + 64 < M) ? s_col[qi][lane + 64] : ~0ull;
            b = bitonic64(b, lane);
            const u64 bs = __shfl(b, lane & 15);
            u64 mv = (lane < 16) ? a : ((lane < 32) ? bs : ~0ull);
            mv = bitonic64(mv, lane);
            if (lane < KNN) {
                oidx[q * KNN + lane] = (int)(mv & 0xffffffffu);
                od2 [q * KNN + lane] = __uint_as_float((unsigned)(mv >> 32));
            }
        }
    }
}

// ---------------------------------------------------------------------------
// Kernel C: fused per-point attention, v10 (R16 version, verbatim).
// ---------------------------------------------------------------------------
__global__ __launch_bounds__(256) void fused_kernel(
    const float* __restrict__ p,
    const float* __restrict__ xqg, const u16* __restrict__ xkg, const u16* __restrict__ xvg,
    const int* __restrict__ nidx, const float* __restrict__ nd2,
    const float* __restrict__ Wp1, const float* __restrict__ bp1,
    const float* __restrict__ g1,  const float* __restrict__ be1,
    const float* __restrict__ Wp2, const float* __restrict__ bp2,
    const float* __restrict__ g2,  const float* __restrict__ be2,
    const u16* __restrict__ w1p,   const float* __restrict__ bw1,
    const float* __restrict__ g3,  const float* __restrict__ be3,
    const u16* __restrict__ w2p,   const float* __restrict__ bw2,
    float* __restrict__ out) {
    const int i = blockIdx.x;
    const int t = threadIdx.x;

    __shared__ __align__(16) u16 s_wv[2048];    // [16 nbr][128 ch] bf16, swizzled
    __shared__ __align__(16) u16 s_rr[256];     // [16 nbr][16 m]  bf16, plain
    __shared__ float s_val[16][132];
    __shared__ float s_wnT[16][20];             // [m][nbr] (transposed)

    const int k  = t >> 4;      // neighbor 0..15
    const int tl = t & 15;      // channel-group
    const int c0 = tl * 8;

    // ---- issue long-latency gathers first ----
    const int   jn  = nidx[i * KNN + k];
    const float d2v = nd2[i * KNN + k];
    const uint4 ku = *(const uint4*)&xkg[(size_t)jn * CCH + c0];   // 8 bf16
    const uint4 vu = *(const uint4*)&xvg[(size_t)jn * CCH + c0];   // 8 bf16

    // ---- phase 1: pr + wv (regs) + val (LDS) ----
    const float dw  = __expf(-sqrtf(fmaxf(d2v, 0.f)));
    const float prx = p[jn * 3 + 0] - p[i * 3 + 0];
    const float pry = p[jn * 3 + 1] - p[i * 3 + 1];
    const float prz = p[jn * 3 + 2] - p[i * 3 + 2];
    float tt[3];
    #pragma unroll
    for (int e = 0; e < 3; ++e) {
        float v = prx * Wp1[0 * 3 + e] + pry * Wp1[1 * 3 + e] + prz * Wp1[2 * 3 + e] + bp1[e];
        v = v * (g1[e] * BN_RS) + be1[e];
        tt[e] = fmaxf(v, 0.f);
    }

    float xk8[8], xv8[8];
    bf8_to_f(ku, xk8);
    bf8_to_f(vu, xv8);

    float wv8[8];
    #pragma unroll
    for (int h = 0; h < 2; ++h) {
        const int cc = c0 + h * 4;
        const float4 w0  = *(const float4*)&Wp2[cc];
        const float4 w1  = *(const float4*)&Wp2[128 + cc];
        const float4 w2  = *(const float4*)&Wp2[256 + cc];
        const float4 bp  = *(const float4*)&bp2[cc];
        const float4 xq4 = *(const float4*)&xqg[(size_t)i * CCH + cc];
        const float4 gg  = *(const float4*)&g2[cc];
        const float4 bb  = *(const float4*)&be2[cc];
        float4 val4;
        {
            const float pr = tt[0] * w0.x + tt[1] * w1.x + tt[2] * w2.x + bp.x;
            wv8[h * 4 + 0] = fmaxf(((xq4.x - xk8[h * 4 + 0]) + pr) * (gg.x * BN_RS) + bb.x, 0.f);
            val4.x = xv8[h * 4 + 0] * dw + pr;
        }
        {
            const float pr = tt[0] * w0.y + tt[1] * w1.y + tt[2] * w2.y + bp.y;
            wv8[h * 4 + 1] = fmaxf(((xq4.y - xk8[h * 4 + 1]) + pr) * (gg.y * BN_RS) + bb.y, 0.f);
            val4.y = xv8[h * 4 + 1] * dw + pr;
        }
        {
            const float pr = tt[0] * w0.z + tt[1] * w1.z + tt[2] * w2.z + bp.z;
            wv8[h * 4 + 2] = fmaxf(((xq4.z - xk8[h * 4 + 2]) + pr) * (gg.z * BN_RS) + bb.z, 0.f);
            val4.z = xv8[h * 4 + 2] * dw + pr;
        }
        {
            const float pr = tt[0] * w0.w + tt[1] * w1.w + tt[2] * w2.w + bp.w;
            wv8[h * 4 + 3] = fmaxf(((xq4.w - xk8[h * 4 + 3]) + pr) * (gg.w * BN_RS) + bb.w, 0.f);
            val4.w = xv8[h * 4 + 3] * dw + pr;
        }
        *(float4*)&s_val[k][cc] = val4;
    }

    // wv -> bf16 -> s_wv, swizzled, one b128 write
    {
        uint4 wp;
        wp.x = (unsigned)f2bf(wv8[0]) | ((unsigned)f2bf(wv8[1]) << 16);
        wp.y = (unsigned)f2bf(wv8[2]) | ((unsigned)f2bf(wv8[3]) << 16);
        wp.z = (unsigned)f2bf(wv8[4]) | ((unsigned)f2bf(wv8[5]) << 16);
        wp.w = (unsigned)f2bf(wv8[6]) | ((unsigned)f2bf(wv8[7]) << 16);
        const int byte = k * 256 + ((c0 * 2) ^ ((k & 7) << 4));
        *(uint4*)((char*)s_wv + byte) = wp;
    }
    __syncthreads();                                   // B0

    // ---- wave 0 only: MFMA w-MLP + softmax ----
    if (t < 64) {
        const int l  = t;
        const int lr = l & 15;      // A row / B col
        const int lg = l >> 4;      // k-chunk group

        f32x4 acc = {0.f, 0.f, 0.f, 0.f};
        #pragma unroll
        for (int c = 0; c < 4; ++c) {
            const int off = ((lg * 16 + 64 * c) ^ ((lr & 7) << 4));
            const short8 a = *(const short8*)((const char*)s_wv + lr * 256 + off);
            const short8 b = *(const short8*)((const char*)w1p  + lr * 256 + off);
            acc = __builtin_amdgcn_mfma_f32_16x16x32_bf16(a, b, acc, 0, 0, 0);
        }
        const float bw1m = bw1[lr];
        const float g3m  = g3[lr] * BN_RS;
        const float be3m = be3[lr];
        #pragma unroll
        for (int r = 0; r < 4; ++r) {
            const float rr = fmaxf((acc[r] + bw1m) * g3m + be3m, 0.f);
            *(u16*)((char*)s_rr + (lg * 4 + r) * 32 + lr * 2) = f2bf(rr);
        }

        short8 a2 = (short8){0, 0, 0, 0, 0, 0, 0, 0};
        short8 b2 = (short8){0, 0, 0, 0, 0, 0, 0, 0};
        if (lg < 2) {
            a2 = *(const short8*)((const char*)s_rr + lr * 32 + lg * 16);
            b2 = *(const short8*)((const char*)w2p + (lg * 16 + lr) * 16);
        }
        f32x4 acc2 = {0.f, 0.f, 0.f, 0.f};
        acc2 = __builtin_amdgcn_mfma_f32_16x16x32_bf16(a2, b2, acc2, 0, 0, 0);

        const float bw2m = bw2[lr];
        float w2v[4];
        #pragma unroll
        for (int r = 0; r < 4; ++r) w2v[r] = acc2[r] + bw2m;

        float mx = fmaxf(fmaxf(w2v[0], w2v[1]), fmaxf(w2v[2], w2v[3]));
        mx = fmaxf(mx, __shfl_xor(mx, 16));
        mx = fmaxf(mx, __shfl_xor(mx, 32));
        float ev[4], ss = 0.f;
        #pragma unroll
        for (int r = 0; r < 4; ++r) { ev[r] = __expf(w2v[r] - mx); ss += ev[r]; }
        ss += __shfl_xor(ss, 16);
        ss += __shfl_xor(ss, 32);
        const float inv = __fdividef(1.f, ss);
        #pragma unroll
        for (int r = 0; r < 4; ++r) s_wnT[lr][lg * 4 + r] = ev[r] * inv;
    }
    __syncthreads();                                   // B1

    // ---- phase 4: out[c] = sum_k val[k][c] * wnT[c & 15][k] ----
    if (t < 128) {
        const int c = t, mc = t & 15;
        const float4 wn0 = *(const float4*)&s_wnT[mc][0];
        const float4 wn1 = *(const float4*)&s_wnT[mc][4];
        const float4 wn2 = *(const float4*)&s_wnT[mc][8];
        const float4 wn3 = *(const float4*)&s_wnT[mc][12];
        float o = 0.f;
        o += s_val[0][c]  * wn0.x; o += s_val[1][c]  * wn0.y;
        o += s_val[2][c]  * wn0.z; o += s_val[3][c]  * wn0.w;
        o += s_val[4][c]  * wn1.x; o += s_val[5][c]  * wn1.y;
        o += s_val[6][c]  * wn1.z; o += s_val[7][c]  * wn1.w;
        o += s_val[8][c]  * wn2.x; o += s_val[9][c]  * wn2.y;
        o += s_val[10][c] * wn2.z; o += s_val[11][c] * wn2.w;
        o += s_val[12][c] * wn3.x; o += s_val[13][c] * wn3.y;
        o += s_val[14][c] * wn3.z; o += s_val[15][c] * wn3.w;
        out[(size_t)i * CCH + c] = o;
    }
}

// ---------------------------------------------------------------------------
extern "C" void kernel_launch(void* const* d_in, const int* in_sizes, int n_in,
                              void* d_out, int out_size, void* d_ws, size_t ws_size,
                              hipStream_t stream) {
    (void)in_sizes; (void)n_in; (void)out_size; (void)ws_size;
    const float* p   = (const float*)d_in[0];
    const float* x   = (const float*)d_in[1];
    const float* Wq  = (const float*)d_in[2];
    const float* bq  = (const float*)d_in[3];
    const float* Wk  = (const float*)d_in[4];
    const float* bk  = (const float*)d_in[5];
    const float* Wv  = (const float*)d_in[6];
    const float* bv  = (const float*)d_in[7];
    const float* Wp1 = (const float*)d_in[8];
    const float* bp1 = (const float*)d_in[9];
    const float* g1  = (const float*)d_in[10];
    const float* be1 = (const float*)d_in[11];
    const float* Wp2 = (const float*)d_in[12];
    const float* bp2 = (const float*)d_in[13];
    const float* g2  = (const float*)d_in[14];
    const float* be2 = (const float*)d_in[15];
    const float* Ww1 = (const float*)d_in[16];
    const float* bw1 = (const float*)d_in[17];
    const float* g3  = (const float*)d_in[18];
    const float* be3 = (const float*)d_in[19];
    const float* Ww2 = (const float*)d_in[20];
    const float* bw2 = (const float*)d_in[21];
    float* out = (float*)d_out;

    // workspace layout
    char* ws = (char*)d_ws;
    int*    idxb  = (int*)ws;                                   // 512 KB
    float*  d2b   = (float*)(ws + (size_t)512 * 1024);          // 512 KB
    float*  xqb   = (float*)(ws + (size_t)1 * 1024 * 1024);     // 4 MB
    u16*    xkb16 = (u16*)(ws + (size_t)5 * 1024 * 1024);       // 2 MB
    u16*    xvb16 = (u16*)(ws + (size_t)7 * 1024 * 1024);       // 2 MB
    float4* c4b   = (float4*)(ws + (size_t)9 * 1024 * 1024);    // 128 KB
    u16*    w1p   = (u16*)(ws + (size_t)9 * 1024 * 1024 + 128 * 1024);   // 4 KB
    u16*    w2p   = (u16*)(ws + (size_t)9 * 1024 * 1024 + 132 * 1024);   // 512 B
    u16*    wpack = (u16*)(ws + (size_t)9 * 1024 * 1024 + 136 * 1024);   // 96 KB

    pack_kernel<<<dim3(NPTS / 256), dim3(256), 0, stream>>>(
        p, c4b, Ww1, Ww2, Wq, Wk, Wv, w1p, w2p, wpack);
    knn_gemm_kernel<<<dim3(1024 + 768), dim3(256), 0, stream>>>(
        c4b, idxb, d2b, x, bq, bk, bv, wpack, xqb, xkb16, xvb16);
    fused_kernel<<<dim3(NPTS), dim3(256), 0, stream>>>(
        p, xqb, xkb16, xvb16, idxb, d2b,
        Wp1, bp1, g1, be1, Wp2, bp2, g2, be2, w1p, bw1, g3, be3, w2p, bw2, out);
}